// Round 1
// baseline (32.777 us; speedup 1.0000x reference)
//
#include <hip/hip_runtime.h>
#include <math.h>

// LogicConv2d: out[b,u] = soft-logic-mix(a[b,u], b[b,u]; w[u]) where
//   a[b,u] = dot(patch(x[b], u/9), softmax(sel_a_logits[u]))
//   b[b,u] = dot(patch(x[b], u/9), softmax(sel_b_logits[u]))
// Mix collapses to Cab*ab + Ca*a + Cb*b + C0 (per-unit coefficients).
//
// Decomposition: block = 256 threads (4 waves) <-> 64 batches.
// lane <-> batch, wave w handles units u = w, w+4, ..., so u is
// wave-uniform (weight LDS reads broadcast). Input and output both go
// through LDS tiles for fully coalesced float4 global traffic.

#define NB      131072
#define NUNITS  81
#define BPB     64            // batches per block
#define THREADS 256
#define NBLK    (NB / BPB)    // 2048
#define REC     24            // floats per unit record: sa[9] sb[9] coef[4] pad[2]
#define CHUNKS  1296          // BPB*81/4 float4 per tile

__global__ __launch_bounds__(THREADS)
void logic_conv2d_kernel(const float* __restrict__ x,
                         const float* __restrict__ sa_logits,
                         const float* __restrict__ sb_logits,
                         const float* __restrict__ op_logits,
                         float* __restrict__ out)
{
    __shared__ float s_in [BPB * 81];     // 20736 B, linear batch-major
    __shared__ float s_out[BPB * 81];     // 20736 B, [batch][u]
    __shared__ float s_tab[NUNITS * REC]; // 7776 B

    const int tid  = threadIdx.x;
    const int lane = tid & 63;
    const int wave = tid >> 6;
    const size_t b0 = (size_t)blockIdx.x * BPB;

    // ---- stage input tile: 64 batches x 81 floats, coalesced float4 ----
    {
        const float4* gsrc = (const float4*)(x + b0 * 81);
        float4* s4 = (float4*)s_in;
        #pragma unroll
        for (int k = 0; k < 6; ++k) {
            int j = tid + k * THREADS;
            if (j < CHUNKS) s4[j] = gsrc[j];
        }
    }

    // ---- per-block weight tables (2754 logits, L2-resident) ----
    if (tid < 81) {
        const int u = tid;
        float v[9], m = -1e30f;
        #pragma unroll
        for (int i = 0; i < 9; ++i) { v[i] = sa_logits[u * 9 + i]; m = fmaxf(m, v[i]); }
        float s = 0.f;
        #pragma unroll
        for (int i = 0; i < 9; ++i) { v[i] = expf(v[i] - m); s += v[i]; }
        const float r = 1.f / s;
        #pragma unroll
        for (int i = 0; i < 9; ++i) s_tab[u * REC + i] = v[i] * r;
    } else if (tid < 162) {
        const int u = tid - 81;
        float v[9], m = -1e30f;
        #pragma unroll
        for (int i = 0; i < 9; ++i) { v[i] = sb_logits[u * 9 + i]; m = fmaxf(m, v[i]); }
        float s = 0.f;
        #pragma unroll
        for (int i = 0; i < 9; ++i) { v[i] = expf(v[i] - m); s += v[i]; }
        const float r = 1.f / s;
        #pragma unroll
        for (int i = 0; i < 9; ++i) s_tab[u * REC + 9 + i] = v[i] * r;
    } else if (tid < 243) {
        const int u = tid - 162;
        float v[16], m = -1e30f;
        #pragma unroll
        for (int i = 0; i < 16; ++i) { v[i] = op_logits[u * 16 + i]; m = fmaxf(m, v[i]); }
        float s = 0.f;
        #pragma unroll
        for (int i = 0; i < 16; ++i) { v[i] = expf(v[i] - m); s += v[i]; }
        const float r = 1.f / s;
        #pragma unroll
        for (int i = 0; i < 16; ++i) v[i] *= r;
        // out = Cab*ab + Ca*a + Cb*b + C0
        const float cab = v[1] - v[2] - v[4] - 2.f*v[6] - v[7] + v[8] + 2.f*v[9]
                        + v[11] + v[13] - v[14];
        const float ca  = v[2] + v[3] + v[6] + v[7] - v[8] - v[9] - v[12] - v[13];
        const float cb  = v[4] + v[5] + v[6] + v[7] - v[8] - v[9] - v[10] - v[11];
        const float c0  = v[8] + v[9] + v[10] + v[11] + v[12] + v[13] + v[14] + v[15];
        s_tab[u * REC + 18] = cab;
        s_tab[u * REC + 19] = ca;
        s_tab[u * REC + 20] = cb;
        s_tab[u * REC + 21] = c0;
    }

    __syncthreads();

    // ---- compute: lane = batch, wave-uniform u ----
    {
        const float* my_in = s_in + lane * 81;
        for (int u = wave; u < NUNITS; u += 4) {
            const int p    = u / 9;                 // wave-uniform
            const int base = (p / 3) * 27 + (p % 3) * 3;
            const float i0 = my_in[base + 0],  i1 = my_in[base + 1],  i2 = my_in[base + 2];
            const float i3 = my_in[base + 9],  i4 = my_in[base + 10], i5 = my_in[base + 11];
            const float i6 = my_in[base + 18], i7 = my_in[base + 19], i8 = my_in[base + 20];
            const float* wr = s_tab + u * REC;     // broadcast reads
            const float a = i0*wr[0] + i1*wr[1] + i2*wr[2]
                          + i3*wr[3] + i4*wr[4] + i5*wr[5]
                          + i6*wr[6] + i7*wr[7] + i8*wr[8];
            const float b = i0*wr[9]  + i1*wr[10] + i2*wr[11]
                          + i3*wr[12] + i4*wr[13] + i5*wr[14]
                          + i6*wr[15] + i7*wr[16] + i8*wr[17];
            const float res = wr[21] + wr[19]*a + wr[20]*b + wr[18]*(a*b);
            s_out[lane * 81 + u] = res;            // stride-81: 2-way bank alias = free
        }
    }

    __syncthreads();

    // ---- coalesced writeback ----
    {
        const float4* s4 = (const float4*)s_out;
        float4* gdst = (float4*)(out + b0 * 81);
        #pragma unroll
        for (int k = 0; k < 6; ++k) {
            int j = tid + k * THREADS;
            if (j < CHUNKS) gdst[j] = s4[j];
        }
    }
}

extern "C" void kernel_launch(void* const* d_in, const int* in_sizes, int n_in,
                              void* d_out, int out_size, void* d_ws, size_t ws_size,
                              hipStream_t stream)
{
    const float* x  = (const float*)d_in[0];
    const float* sa = (const float*)d_in[1];
    const float* sb = (const float*)d_in[2];
    const float* op = (const float*)d_in[3];
    float* out = (float*)d_out;
    logic_conv2d_kernel<<<NBLK, THREADS, 0, stream>>>(x, sa, sb, op, out);
}